// Round 4
// baseline (139.235 us; speedup 1.0000x reference)
//
#include <hip/hip_runtime.h>

#define IMH 512
#define IMW 512
#define TW 32
#define TH 8
#define HW_ 34
#define HH_ 10
#define NHALO 340            // 34*10 halo pixels
#define NTHR 512

// Channel layout per halo pixel (32 floats = 8 float4 chunks, XOR-swizzled:
// logical chunk k of pixel p lives at physical slot (k+p)&7):
//   ch 0..2   : Z
//   ch 3..14  : w_pre(s,ij), ij=0..3, at 3 + ij*3 + s
//   ch 15     : pad
//   ch 16..30 : w_pre(s,ij), ij=4..8, at 16 + (ij-4)*3 + s
//   ch 31     : pad
// ij-groups never straddle the half boundary -> wave-role q=0 owns chunks
// 0..3, q=1 owns chunks 4..7: stage A is race-free in-place, stage B reads
// only the chunks its groups need. q is wave-uniform (tid>>6 & 1).
__global__ __launch_bounds__(NTHR, 1)
void hmm_fused(const float* __restrict__ obs,
               const float* __restrict__ P,       // P[o*3+s]
               const float* __restrict__ u_k,
               const float* __restrict__ w_k,     // pix*27 + s*9 + ij
               const float* __restrict__ conv_w,  // (S_out,S_in,3,3)
               const float* __restrict__ conv_b,
               float* __restrict__ out) {
    __shared__ float4 lds4[NHALO * 8];             // 43,520 B -> 3 blocks/CU
    float* lds = (float*)lds4;

    const int tid  = threadIdx.x;
    const int w0   = blockIdx.x * TW;
    const int h0   = blockIdx.y * TH;
    const int lane = tid & 63;
    const int wave = tid >> 6;       // 0..7
    const int q    = wave & 1;       // wave-uniform role
    const int grp  = wave >> 1;      // 0..3

    float Pm[9];
#pragma unroll
    for (int i = 0; i < 9; ++i) Pm[i] = P[i];

    // ---- Stage 0: coalesced staging of w_k, permuted raw c=s*9+ij -> cd
    for (int r = 0; r < HH_; ++r) {
        const int hh = h0 + r - 1;
        if (hh < 0 || hh >= IMH) continue;
        const long long gbase = ((long long)hh * IMW + (w0 - 1)) * 27;
        for (int f = tid; f < HW_ * 27; f += NTHR) {   // 918 floats, coalesced
            const int p = f / 27;
            const int c = f - p * 27;
            const int ww = w0 - 1 + p;
            float v = 0.0f;
            if (ww >= 0 && ww < IMW) v = w_k[gbase + f];
            const int s  = c / 9;
            const int ij = c - s * 9;
            const int cd = (ij < 4) ? (3 + ij * 3 + s) : (16 + (ij - 4) * 3 + s);
            const int pr = r * HW_ + p;
            lds[pr * 32 + (((cd >> 2) + pr) & 7) * 4 + (cd & 3)] = v;
        }
    }

    float cw[81];                                  // uniform -> s_load/SGPRs
#pragma unroll
    for (int i = 0; i < 81; ++i) cw[i] = conv_w[i];
    const float cb0 = conv_b[0], cb1 = conv_b[1], cb2 = conv_b[2];

    __syncthreads();

    // ---- Stage A: in-place transform; q=0 -> chunks 0..3, q=1 -> chunks 4..7
    for (int p = grp * 64 + lane; p < NHALO; p += 256) {
        const int rr = p / HW_;
        const int cc = p - rr * HW_;
        const int hh = h0 + rr - 1;
        const int ww = w0 + cc - 1;
        const int base = p * 8;
        const int kb = q * 4;
        float oc[16];
        if ((unsigned)hh < IMH && (unsigned)ww < IMW) {
            const int pix = hh * IMW + ww;
            const float ov[3] = {obs[pix*3+0], obs[pix*3+1], obs[pix*3+2]};
            const float us[3] = {u_k[pix*3+0], u_k[pix*3+1], u_k[pix*3+2]};
            float b[3], Bu[3], bu = 0.f;
#pragma unroll
            for (int s = 0; s < 3; ++s) {
                b[s] = Pm[s] * ov[0] + Pm[3+s] * ov[1] + Pm[6+s] * ov[2];
                Bu[s] = b[s] * us[s]; bu += Bu[s];
            }
            const float inv_bu = 1.0f / bu;
            float Z[3];
#pragma unroll
            for (int s = 0; s < 3; ++s) Z[s] = Bu[s] * inv_bu;

            float rv[16];
#pragma unroll
            for (int k = 0; k < 4; ++k) {
                const float4 v = lds4[base + ((kb + k + p) & 7)];
                rv[4*k+0] = v.x; rv[4*k+1] = v.y; rv[4*k+2] = v.z; rv[4*k+3] = v.w;
            }
            if (q == 0) {
                oc[0] = Z[0]; oc[1] = Z[1]; oc[2] = Z[2];
#pragma unroll
                for (int ij = 0; ij < 4; ++ij) {
                    const int i = ij / 3, j = ij % 3;
                    float du[3], sdu = 0.f;
#pragma unroll
                    for (int s = 0; s < 3; ++s) {
                        float d = b[s] * rv[3 + ij*3 + s];
                        if (s == j) d += ov[i] * us[s];
                        du[s] = d; sdu += d;
                    }
#pragma unroll
                    for (int s = 0; s < 3; ++s)
                        oc[3 + ij*3 + s] = (du[s] - sdu * Z[s]) * inv_bu;
                }
                oc[15] = 0.f;
            } else {
#pragma unroll
                for (int ij = 4; ij < 9; ++ij) {
                    const int i = ij / 3, j = ij % 3;
                    float du[3], sdu = 0.f;
#pragma unroll
                    for (int s = 0; s < 3; ++s) {
                        float d = b[s] * rv[(ij-4)*3 + s];
                        if (s == j) d += ov[i] * us[s];
                        du[s] = d; sdu += d;
                    }
#pragma unroll
                    for (int s = 0; s < 3; ++s)
                        oc[(ij-4)*3 + s] = (du[s] - sdu * Z[s]) * inv_bu;
                }
                oc[15] = 0.f;
            }
        } else {
#pragma unroll
            for (int i = 0; i < 16; ++i) oc[i] = 0.f;
        }
#pragma unroll
        for (int k = 0; k < 4; ++k)
            lds4[base + ((kb + k + p) & 7)] =
                make_float4(oc[4*k], oc[4*k+1], oc[4*k+2], oc[4*k+3]);
    }

    __syncthreads();

    // ---- Stage B: 2 waves per 64-pixel group; q=0 -> group0 + ij0..3,
    //               q=1 -> group0(dup) + ij4..8
    const int pxi = grp * 64 + lane;      // 0..255
    const int tx = pxi & 31, ty = pxi >> 5;
    const int hp = (ty + 1) * HW_ + tx + 1;

    float yv0 = cb0, yv1 = cb1, yv2 = cb2;
    float acc[15];
#pragma unroll
    for (int i = 0; i < 15; ++i) acc[i] = 0.f;

    if (q == 0) {
#pragma unroll
        for (int ky = 0; ky < 3; ++ky) {
#pragma unroll
            for (int kx = 0; kx < 3; ++kx) {
                const int tap = ky * 3 + kx;
                const int pn = hp + (ky - 1) * HW_ + (kx - 1);
                float v[16];
#pragma unroll
                for (int k = 0; k < 4; ++k) {
                    const float4 t = lds4[pn*8 + ((k + pn) & 7)];
                    v[4*k+0] = t.x; v[4*k+1] = t.y; v[4*k+2] = t.z; v[4*k+3] = t.w;
                }
#pragma unroll
                for (int si = 0; si < 3; ++si) {
                    const float wa = cw[0*27 + si*9 + tap];
                    const float wb = cw[1*27 + si*9 + tap];
                    const float wc = cw[2*27 + si*9 + tap];
                    yv0 += wa * v[si]; yv1 += wb * v[si]; yv2 += wc * v[si];
#pragma unroll
                    for (int ij = 0; ij < 4; ++ij) {
                        const float val = v[3 + ij*3 + si];
                        acc[ij*3+0] += wa * val;
                        acc[ij*3+1] += wb * val;
                        acc[ij*3+2] += wc * val;
                    }
                }
            }
        }
    } else {
#pragma unroll
        for (int ky = 0; ky < 3; ++ky) {
#pragma unroll
            for (int kx = 0; kx < 3; ++kx) {
                const int tap = ky * 3 + kx;
                const int pn = hp + (ky - 1) * HW_ + (kx - 1);
                const float4 t0 = lds4[pn*8 + ((0 + pn) & 7)];   // ch0..3 (Z)
                const float z[3] = {t0.x, t0.y, t0.z};
                float v[16];
#pragma unroll
                for (int k = 0; k < 4; ++k) {
                    const float4 t = lds4[pn*8 + ((4 + k + pn) & 7)];
                    v[4*k+0] = t.x; v[4*k+1] = t.y; v[4*k+2] = t.z; v[4*k+3] = t.w;
                }
#pragma unroll
                for (int si = 0; si < 3; ++si) {
                    const float wa = cw[0*27 + si*9 + tap];
                    const float wb = cw[1*27 + si*9 + tap];
                    const float wc = cw[2*27 + si*9 + tap];
                    yv0 += wa * z[si]; yv1 += wb * z[si]; yv2 += wc * z[si];
#pragma unroll
                    for (int ij = 4; ij < 9; ++ij) {
                        const float val = v[(ij-4)*3 + si];
                        acc[(ij-4)*3+0] += wa * val;
                        acc[(ij-4)*3+1] += wb * val;
                        acc[(ij-4)*3+2] += wc * val;
                    }
                }
            }
        }
    }

    // softmax (computed by both roles; identical inputs)
    const float m = fmaxf(yv0, fmaxf(yv1, yv2));
    const float e0 = __expf(yv0 - m), e1 = __expf(yv1 - m), e2 = __expf(yv2 - m);
    const float inv = 1.0f / (e0 + e1 + e2);
    const float p0 = e0 * inv, p1 = e1 * inv, p2 = e2 * inv;

    // softmax JVP -> registers
    float wo[15];
    const int nij = q ? 5 : 4;
#pragma unroll
    for (int ij = 0; ij < 5; ++ij) {
        if (ij < nij) {
            const float a0 = acc[ij*3+0], a1 = acc[ij*3+1], a2 = acc[ij*3+2];
            const float dot = p0*a0 + p1*a1 + p2*a2;
            wo[ij*3+0] = p0 * (a0 - dot);
            wo[ij*3+1] = p1 * (a1 - dot);
            wo[ij*3+2] = p2 * (a2 - dot);
        }
    }

    __syncthreads();   // all stage-B LDS reads done; reuse LDS for output staging

    // stage outputs: w at lds[pxi*27 + s*9 + ij_global], u at lds[6912 + pxi*3 + s]
    if (q == 0) {
#pragma unroll
        for (int ij = 0; ij < 4; ++ij)
#pragma unroll
            for (int s = 0; s < 3; ++s)
                lds[pxi*27 + s*9 + ij] = wo[ij*3+s];
        lds[6912 + pxi*3 + 0] = p0;
        lds[6912 + pxi*3 + 1] = p1;
        lds[6912 + pxi*3 + 2] = p2;
    } else {
#pragma unroll
        for (int ij = 0; ij < 5; ++ij)
#pragma unroll
            for (int s = 0; s < 3; ++s)
                lds[pxi*27 + s*9 + (ij + 4)] = wo[ij*3+s];
    }
    __syncthreads();

    // coalesced float4 stores
    float* outw = out + IMH * IMW * 3;
    for (int idx = tid; idx < 1728; idx += NTHR) {          // 216 float4 per tile row
        const int r = idx / 216;
        const int c4 = idx - r * 216;
        float4* dst = (float4*)(outw + ((size_t)(h0 + r) * IMW + w0) * 27);
        dst[c4] = lds4[idx];
    }
    for (int idx = tid; idx < 192; idx += NTHR) {           // 24 float4 per tile row
        const int r = idx / 24;
        const int c4 = idx - r * 24;
        float4* dst = (float4*)(out + ((size_t)(h0 + r) * IMW + w0) * 3);
        dst[c4] = lds4[1728 + idx];
    }
}

extern "C" void kernel_launch(void* const* d_in, const int* in_sizes, int n_in,
                              void* d_out, int out_size, void* d_ws, size_t ws_size,
                              hipStream_t stream) {
    const float* obs    = (const float*)d_in[0];
    const float* P      = (const float*)d_in[1];
    const float* u_k    = (const float*)d_in[2];
    const float* w_k    = (const float*)d_in[3];
    const float* conv_w = (const float*)d_in[4];
    const float* conv_b = (const float*)d_in[5];
    float* out = (float*)d_out;

    dim3 grid(IMW / TW, IMH / TH);   // (16, 64) = 1024 blocks
    hmm_fused<<<grid, NTHR, 0, stream>>>(obs, P, u_k, w_k, conv_w, conv_b, out);
}